// Round 7
// baseline (204.132 us; speedup 1.0000x reference)
//
#include <hip/hip_runtime.h>

// Problem: BS=64, N=1024, XC=1024, K=256, YS=768
//   y_k[b,k]   = sum_s y[b,s] * W_y[k,s]
//   z[b,n,k]   = tanh( sum_c x[b,n,c]*W_ch[k,c] + b_ch[k] + y_k[b,k] )
//   out[b*n,k] = softmax_k(z)
// bf16 MFMA GEMM (f32 acc) fused with tanh+softmax epilogue.
// R7: R2's exact structure, but A prefetched 3 K-steps ahead (rotating
//     av[3]) and B issued before A each step, so every in-order vmcnt
//     wait lands on loads >=2 steps (>=1000cy) old: no exposed HBM
//     latency at WRITEA/COMPUTE. B fragments double-buffered (bfrA/bfrB).

#define XC    1024
#define KOUT  256
#define NT    16        // K-steps: 1024 / 64
#define LDSZ  16384     // A double-buffer: 2 x 8KB (epilogue scratch aliases)

typedef float        f32x4_t  __attribute__((ext_vector_type(4)));
typedef unsigned int u32x4_t  __attribute__((ext_vector_type(4)));
typedef unsigned int u32x2_t  __attribute__((ext_vector_type(2)));
typedef __bf16       bf16x8_t __attribute__((ext_vector_type(8)));

__device__ __forceinline__ unsigned short f2bf(float f) {
  unsigned int u = __float_as_uint(f);
  u += 0x7fffu + ((u >> 16) & 1u);        // RNE
  return (unsigned short)(u >> 16);
}

__device__ __forceinline__ float fast_tanh(float v) {
  float e = __expf(2.0f * v);
  return 1.0f - 2.0f / (e + 1.0f);
}

// lgkm-only barrier: ds_writes visible, global loads STAY IN FLIGHT.
#define LGKM_BARRIER() do {                                  \
    asm volatile("s_waitcnt lgkmcnt(0)" ::: "memory");       \
    __builtin_amdgcn_s_barrier();                            \
    __builtin_amdgcn_sched_barrier(0);                       \
  } while (0)

// ---- prep kernel: blocks 0..255 convert W_ch -> fragment-ordered bf16;
//      blocks 256..319 compute bias[b][k] = y[b]·W_y[k] + b_ch[k] (f32).
// Fragment order: frag(t,wv,kk,ni) = ((t*4+wv)*2+kk)*4+ni, 64 lanes x 16B
// dense -> main kernel loads B with fully-coalesced 1KB global_load_dwordx4.
__global__ void prep_kernel(const float* __restrict__ Wch,
                            const float* __restrict__ y,
                            const float* __restrict__ Wy,
                            const float* __restrict__ bch,
                            unsigned short* __restrict__ wbf,
                            float* __restrict__ biasws) {
  if (blockIdx.x < 256) {
    const int k = blockIdx.x;            // 0..255
    const int u = threadIdx.x;           // 0..255 ; c0 = 4u
    f32x4_t v = ((const f32x4_t*)(Wch + k * XC))[u];
    const int c0   = u << 2;
    const int t    = c0 >> 6;            // K-step tile
    const int ch   = (c0 & 63) >> 3;     // 16B chunk within tile
    const int kk   = ch >> 2;
    const int lg   = ch & 3;
    const int half = (c0 >> 2) & 1;      // which 8B of the 16B chunk
    const int wv   = k >> 6;
    const int ni   = (k >> 4) & 3;
    const int lr   = k & 15;
    const int lane = (lg << 4) | lr;
    unsigned int lo = (unsigned int)f2bf(v.x) | ((unsigned int)f2bf(v.y) << 16);
    unsigned int hi = (unsigned int)f2bf(v.z) | ((unsigned int)f2bf(v.w) << 16);
    char* p = (char*)wbf +
              ((size_t)((((t << 2) + wv) * 2 + kk) * 4 + ni) << 10) +
              (lane << 4) + (half << 3);
    *(u32x2_t*)p = (u32x2_t){lo, hi};
  } else {
    __shared__ __align__(16) float ys[768];
    const int b = blockIdx.x - 256;      // 0..63
    const int k = threadIdx.x;           // 0..255
    for (int i = k; i < 768; i += 256) ys[i] = y[b * 768 + i];
    __syncthreads();
    const f32x4_t* w4 = (const f32x4_t*)(Wy + k * 768);
    const f32x4_t* y4 = (const f32x4_t*)ys;
    float s = 0.f;
#pragma unroll 8
    for (int i = 0; i < 192; ++i) {
      f32x4_t w = w4[i], a = y4[i];
      s = fmaf(w.x, a.x, s); s = fmaf(w.y, a.y, s);
      s = fmaf(w.z, a.z, s); s = fmaf(w.w, a.w, s);
    }
    biasws[b * 256 + k] = s + bch[k];
  }
}

// ---- main fused kernel: 64 rows/block x full 256 cols; BK=64.
// A: reg-staged f32->bf16, XOR-swizzled ds_write, dbuf LDS (16KB).
// B: fragment-ordered global loads straight to double-buffered registers.
__global__ __launch_bounds__(256, 3) void fused_kernel(
    const float* __restrict__ x, const unsigned short* __restrict__ wbf,
    const float* __restrict__ bias, float* __restrict__ out) {
  __shared__ __align__(16) unsigned char smem[LDSZ];
  const int tid = threadIdx.x;
  const int l   = tid & 63;
  const int wv  = tid >> 6;            // wave 0..3 -> output cols [64w,64w+64)
  const int lr  = l & 15;
  const int lg  = l >> 4;
  const int m0  = blockIdx.x << 6;     // first of 64 rows
  const int bidx = m0 >> 10;           // batch index
  const int rr  = tid >> 4;            // A-stage: row-within-16-group
  const int c4  = tid & 15;            // A-stage: float4 column chunk

  f32x4_t acc[4][4];
#pragma unroll
  for (int i = 0; i < 4; ++i)
#pragma unroll
    for (int j = 0; j < 4; ++j) acc[i][j] = (f32x4_t){0.f, 0.f, 0.f, 0.f};

  const float* xb = x + (size_t)m0 * XC + (size_t)rr * XC + (c4 << 2);
  const char* wsrc = (const char*)wbf + (wv << 13) + (l << 4);
  f32x4_t av[3][4];                    // rotating 3-deep A prefetch
  bf16x8_t bfrA[8], bfrB[8];           // [kk*4+nj], double-buffered

#define LOADA(slot, tt) do {                                                 \
    _Pragma("unroll")                                                        \
    for (int j = 0; j < 4; ++j)                                              \
      av[slot][j] = *(const f32x4_t*)(xb + (size_t)(j << 4) * XC + ((tt) << 6));\
  } while (0)

#define LOADB(dst, tt) do {                                                  \
    const char* g = wsrc + (size_t)(tt) * 32768;                             \
    _Pragma("unroll")                                                        \
    for (int f = 0; f < 8; ++f)                                              \
      dst[f] = __builtin_bit_cast(bf16x8_t, *(const u32x4_t*)(g + (f << 10)));\
  } while (0)

#define WRITEA(slot, buf) do {                                               \
    _Pragma("unroll")                                                        \
    for (int j = 0; j < 4; ++j) {                                            \
      const int row = (j << 4) + rr;                                         \
      unsigned int lo = (unsigned int)f2bf(av[slot][j].x) |                  \
                        ((unsigned int)f2bf(av[slot][j].y) << 16);           \
      unsigned int hi = (unsigned int)f2bf(av[slot][j].z) |                  \
                        ((unsigned int)f2bf(av[slot][j].w) << 16);           \
      char* p = (char*)smem + ((buf) << 13) + row * 128 +                    \
                (((c4 >> 1) ^ (row & 7)) << 4) + ((c4 & 1) << 3);            \
      *(u32x2_t*)p = (u32x2_t){lo, hi};                                      \
    }                                                                        \
  } while (0)

#define COMPUTE(buf, bsrc) do {                                              \
    const u32x4_t* aB = (const u32x4_t*)(smem + ((buf) << 13));              \
    _Pragma("unroll")                                                        \
    for (int kk = 0; kk < 2; ++kk) {                                         \
      const int cs = ((kk << 2) | lg) ^ (lr & 7);                            \
      bf16x8_t afr[4];                                                       \
      _Pragma("unroll")                                                      \
      for (int mi = 0; mi < 4; ++mi)                                         \
        afr[mi] = __builtin_bit_cast(bf16x8_t, aB[(((mi << 4) + lr) << 3) + cs]);\
      _Pragma("unroll")                                                      \
      for (int mi = 0; mi < 4; ++mi)                                         \
        _Pragma("unroll")                                                    \
        for (int nj = 0; nj < 4; ++nj)                                       \
          acc[mi][nj] = __builtin_amdgcn_mfma_f32_16x16x32_bf16(             \
              afr[mi], bsrc[(kk << 2) | nj], acc[mi][nj], 0, 0, 0);          \
    }                                                                        \
  } while (0)

  // prologue: B(0), A(0..2) in flight; stage A(0) into buf0.
  LOADB(bfrA, 0);
  LOADA(0, 0);
  LOADA(1, 1);
  LOADA(2, 2);
  WRITEA(0, 0);            // waits vmcnt(4): drains B(0)+A(0); A(1),A(2) fly
  LGKM_BARRIER();

#pragma unroll
  for (int s = 0; s < NT; ++s) {
    // B(s+1) first, then A(s+3): COMPUTE's B(s)-wait drains only loads
    // that are >=2 steps old; A(s+2),A(s+3),B(s+1) stay in flight.
    if (s + 1 < NT) { if (s & 1) LOADB(bfrA, s + 1); else LOADB(bfrB, s + 1); }
    if (s + 3 < NT) LOADA(s % 3, s + 3);
    if (s & 1) COMPUTE(1, bfrB); else COMPUTE(0, bfrA);
    if (s + 1 < NT) {
      WRITEA((s + 1) % 3, (s + 1) & 1);
      LGKM_BARRIER();
    }
  }
  __syncthreads();             // full drain before scratch aliases A buffer

#undef LOADA
#undef LOADB
#undef WRITEA
#undef COMPUTE

  // ---- epilogue: tanh, row-softmax over 256 cols, store
  float* wred    = (float*)smem;           // [4 waves][64 rows]
  float* rowstat = (float*)(smem + 1024);  // [64 rows]

  float brow[4];
#pragma unroll
  for (int ni = 0; ni < 4; ++ni)
    brow[ni] = bias[(bidx << 8) + (wv << 6) + (ni << 4) + lr];

#pragma unroll
  for (int mi = 0; mi < 4; ++mi)
#pragma unroll
    for (int ni = 0; ni < 4; ++ni)
#pragma unroll
      for (int r = 0; r < 4; ++r)
        acc[mi][ni][r] = fast_tanh(acc[mi][ni][r] + brow[ni]);

  // per-row max: 4 local cols, then butterfly over the 16-lane col group
#pragma unroll
  for (int mi = 0; mi < 4; ++mi)
#pragma unroll
    for (int r = 0; r < 4; ++r) {
      float m = fmaxf(fmaxf(acc[mi][0][r], acc[mi][1][r]),
                      fmaxf(acc[mi][2][r], acc[mi][3][r]));
      m = fmaxf(m, __shfl_xor(m, 1));
      m = fmaxf(m, __shfl_xor(m, 2));
      m = fmaxf(m, __shfl_xor(m, 4));
      m = fmaxf(m, __shfl_xor(m, 8));
      if (lr == 0) wred[(wv << 6) + (mi << 4) + (lg << 2) + r] = m;
    }
  __syncthreads();
  if (tid < 64)
    rowstat[tid] = fmaxf(fmaxf(wred[tid], wred[64 + tid]),
                         fmaxf(wred[128 + tid], wred[192 + tid]));
  __syncthreads();

  // exp + per-row sum
#pragma unroll
  for (int mi = 0; mi < 4; ++mi)
#pragma unroll
    for (int r = 0; r < 4; ++r) {
      const int row = (mi << 4) + (lg << 2) + r;
      const float m = rowstat[row];
      float s = 0.f;
#pragma unroll
      for (int ni = 0; ni < 4; ++ni) {
        float e = __expf(acc[mi][ni][r] - m);
        acc[mi][ni][r] = e;
        s += e;
      }
      s += __shfl_xor(s, 1);
      s += __shfl_xor(s, 2);
      s += __shfl_xor(s, 4);
      s += __shfl_xor(s, 8);
      if (lr == 0) wred[(wv << 6) + row] = s;
    }
  __syncthreads();
  if (tid < 64)
    rowstat[tid] = 1.0f / (wred[tid] + wred[64 + tid] +
                           wred[128 + tid] + wred[192 + tid]);
  __syncthreads();

  // normalize + store (16 lanes = 64B dense segments)
#pragma unroll
  for (int mi = 0; mi < 4; ++mi)
#pragma unroll
    for (int r = 0; r < 4; ++r) {
      const int row = (mi << 4) + (lg << 2) + r;
      const float rinv = rowstat[row];
      float* orow = out + (size_t)(m0 + row) * KOUT + (wv << 6) + lr;
#pragma unroll
      for (int ni = 0; ni < 4; ++ni)
        orow[ni << 4] = acc[mi][ni][r] * rinv;
    }
}

extern "C" void kernel_launch(void* const* d_in, const int* in_sizes, int n_in,
                              void* d_out, int out_size, void* d_ws, size_t ws_size,
                              hipStream_t stream) {
  (void)in_sizes; (void)n_in; (void)out_size; (void)ws_size;
  const float* x   = (const float*)d_in[0];
  const float* y   = (const float*)d_in[1];
  const float* Wch = (const float*)d_in[2];
  const float* bch = (const float*)d_in[3];
  const float* Wy  = (const float*)d_in[4];
  float* out = (float*)d_out;
  unsigned short* wbf = (unsigned short*)d_ws;                 // 512 KB
  float* biasws = (float*)((char*)d_ws + 512 * 1024);          // 64 KB

  hipLaunchKernelGGL(prep_kernel, dim3(320), dim3(256), 0, stream,
                     Wch, y, Wy, bch, wbf, biasws);
  hipLaunchKernelGGL(fused_kernel, dim3(1024), dim3(256), 0, stream,
                     x, wbf, biasws, out);
}

// Round 8
// 118.435 us; speedup vs baseline: 1.7236x; 1.7236x over previous
//
#include <hip/hip_runtime.h>

// Problem: BS=64, N=1024, XC=1024, K=256, YS=768
//   y_k[b,k]   = sum_s y[b,s] * W_y[k,s]
//   z[b,n,k]   = tanh( sum_c x[b,n,c]*W_ch[k,c] + b_ch[k] + y_k[b,k] )
//   out[b*n,k] = softmax_k(z)
// bf16 MFMA GEMM (f32 acc) fused with tanh+softmax epilogue.
// R8: R7's 3-deep A prefetch schedule, but ALL pipeline state in named
//     registers with literal indices (16 fully-instantiated steps) --
//     R7's VGPR=84 + 200MB scratch writes proved `av[s%3]` spilled
//     (rule #20). launch_bounds(256,2): ~210 VGPR, no spill, 2 blk/CU.

#define XC    1024
#define KOUT  256
#define NT    16        // K-steps: 1024 / 64
#define LDSZ  16384     // A double-buffer: 2 x 8KB (epilogue scratch aliases)

typedef float        f32x4_t  __attribute__((ext_vector_type(4)));
typedef unsigned int u32x4_t  __attribute__((ext_vector_type(4)));
typedef unsigned int u32x2_t  __attribute__((ext_vector_type(2)));
typedef __bf16       bf16x8_t __attribute__((ext_vector_type(8)));

__device__ __forceinline__ unsigned short f2bf(float f) {
  unsigned int u = __float_as_uint(f);
  u += 0x7fffu + ((u >> 16) & 1u);        // RNE
  return (unsigned short)(u >> 16);
}

__device__ __forceinline__ float fast_tanh(float v) {
  float e = __expf(2.0f * v);
  return 1.0f - 2.0f / (e + 1.0f);
}

// lgkm-only barrier: ds_writes visible, global loads STAY IN FLIGHT.
#define LGKM_BARRIER() do {                                  \
    asm volatile("s_waitcnt lgkmcnt(0)" ::: "memory");       \
    __builtin_amdgcn_s_barrier();                            \
    __builtin_amdgcn_sched_barrier(0);                       \
  } while (0)

// ---- prep kernel: blocks 0..255 convert W_ch -> fragment-ordered bf16;
//      blocks 256..319 compute bias[b][k] = y[b]·W_y[k] + b_ch[k] (f32).
// Fragment order: frag(t,wv,kk,ni) = ((t*4+wv)*2+kk)*4+ni, 64 lanes x 16B
// dense -> main kernel loads B with fully-coalesced 1KB global_load_dwordx4.
__global__ void prep_kernel(const float* __restrict__ Wch,
                            const float* __restrict__ y,
                            const float* __restrict__ Wy,
                            const float* __restrict__ bch,
                            unsigned short* __restrict__ wbf,
                            float* __restrict__ biasws) {
  if (blockIdx.x < 256) {
    const int k = blockIdx.x;            // 0..255
    const int u = threadIdx.x;           // 0..255 ; c0 = 4u
    f32x4_t v = ((const f32x4_t*)(Wch + k * XC))[u];
    const int c0   = u << 2;
    const int t    = c0 >> 6;            // K-step tile
    const int ch   = (c0 & 63) >> 3;     // 16B chunk within tile
    const int kk   = ch >> 2;
    const int lg   = ch & 3;
    const int half = (c0 >> 2) & 1;      // which 8B of the 16B chunk
    const int wv   = k >> 6;
    const int ni   = (k >> 4) & 3;
    const int lr   = k & 15;
    const int lane = (lg << 4) | lr;
    unsigned int lo = (unsigned int)f2bf(v.x) | ((unsigned int)f2bf(v.y) << 16);
    unsigned int hi = (unsigned int)f2bf(v.z) | ((unsigned int)f2bf(v.w) << 16);
    char* p = (char*)wbf +
              ((size_t)((((t << 2) + wv) * 2 + kk) * 4 + ni) << 10) +
              (lane << 4) + (half << 3);
    *(u32x2_t*)p = (u32x2_t){lo, hi};
  } else {
    __shared__ __align__(16) float ys[768];
    const int b = blockIdx.x - 256;      // 0..63
    const int k = threadIdx.x;           // 0..255
    for (int i = k; i < 768; i += 256) ys[i] = y[b * 768 + i];
    __syncthreads();
    const f32x4_t* w4 = (const f32x4_t*)(Wy + k * 768);
    const f32x4_t* y4 = (const f32x4_t*)ys;
    float s = 0.f;
#pragma unroll 8
    for (int i = 0; i < 192; ++i) {
      f32x4_t w = w4[i], a = y4[i];
      s = fmaf(w.x, a.x, s); s = fmaf(w.y, a.y, s);
      s = fmaf(w.z, a.z, s); s = fmaf(w.w, a.w, s);
    }
    biasws[b * 256 + k] = s + bch[k];
  }
}

// ---- main fused kernel: 64 rows/block x full 256 cols; BK=64.
// A: reg-staged f32->bf16, XOR-swizzled ds_write, dbuf LDS (16KB).
// B: fragment-ordered global loads straight to double-buffered registers.
__global__ __launch_bounds__(256, 2) void fused_kernel(
    const float* __restrict__ x, const unsigned short* __restrict__ wbf,
    const float* __restrict__ bias, float* __restrict__ out) {
  __shared__ __align__(16) unsigned char smem[LDSZ];
  const int tid = threadIdx.x;
  const int l   = tid & 63;
  const int wv  = tid >> 6;            // wave 0..3 -> output cols [64w,64w+64)
  const int lr  = l & 15;
  const int lg  = l >> 4;
  const int m0  = blockIdx.x << 6;     // first of 64 rows
  const int bidx = m0 >> 10;           // batch index
  const int rr  = tid >> 4;            // A-stage: row-within-16-group
  const int c4  = tid & 15;            // A-stage: float4 column chunk

  f32x4_t acc[4][4];
#pragma unroll
  for (int i = 0; i < 4; ++i)
#pragma unroll
    for (int j = 0; j < 4; ++j) acc[i][j] = (f32x4_t){0.f, 0.f, 0.f, 0.f};

  const float* xb = x + (size_t)m0 * XC + (size_t)rr * XC + (c4 << 2);
  const char* wsrc = (const char*)wbf + (wv << 13) + (l << 4);
  f32x4_t av0[4], av1[4], av2[4];      // 3-deep A prefetch, NAMED slots
  bf16x8_t bfrA[8], bfrB[8];           // [kk*4+nj], double-buffered

#define LOADA(dst, tt) do {                                                  \
    _Pragma("unroll")                                                        \
    for (int j = 0; j < 4; ++j)                                              \
      dst[j] = *(const f32x4_t*)(xb + (size_t)(j << 4) * XC + ((tt) << 6));  \
  } while (0)

#define LOADB(dst, tt) do {                                                  \
    const char* g = wsrc + (size_t)(tt) * 32768;                             \
    _Pragma("unroll")                                                        \
    for (int f = 0; f < 8; ++f)                                              \
      dst[f] = __builtin_bit_cast(bf16x8_t, *(const u32x4_t*)(g + (f << 10)));\
  } while (0)

#define WRITEA(src, buf) do {                                                \
    _Pragma("unroll")                                                        \
    for (int j = 0; j < 4; ++j) {                                            \
      const int row = (j << 4) + rr;                                         \
      unsigned int lo = (unsigned int)f2bf(src[j].x) |                       \
                        ((unsigned int)f2bf(src[j].y) << 16);                \
      unsigned int hi = (unsigned int)f2bf(src[j].z) |                       \
                        ((unsigned int)f2bf(src[j].w) << 16);                \
      char* p = (char*)smem + ((buf) << 13) + row * 128 +                    \
                (((c4 >> 1) ^ (row & 7)) << 4) + ((c4 & 1) << 3);            \
      *(u32x2_t*)p = (u32x2_t){lo, hi};                                      \
    }                                                                        \
  } while (0)

#define COMPUTE(buf, bsrc) do {                                              \
    const u32x4_t* aB = (const u32x4_t*)(smem + ((buf) << 13));              \
    _Pragma("unroll")                                                        \
    for (int kk = 0; kk < 2; ++kk) {                                         \
      const int cs = ((kk << 2) | lg) ^ (lr & 7);                            \
      bf16x8_t afr[4];                                                       \
      _Pragma("unroll")                                                      \
      for (int mi = 0; mi < 4; ++mi)                                         \
        afr[mi] = __builtin_bit_cast(bf16x8_t, aB[(((mi << 4) + lr) << 3) + cs]);\
      _Pragma("unroll")                                                      \
      for (int mi = 0; mi < 4; ++mi)                                         \
        _Pragma("unroll")                                                    \
        for (int nj = 0; nj < 4; ++nj)                                       \
          acc[mi][nj] = __builtin_amdgcn_mfma_f32_16x16x32_bf16(             \
              afr[mi], bsrc[(kk << 2) | nj], acc[mi][nj], 0, 0, 0);          \
    }                                                                        \
  } while (0)

  // STEP(s): literal args only. bC = B-frags for tile s; bN = buffer for
  // B(s+1); aW = regs holding A(s+1) (staged to LDS after compute);
  // aL = slot receiving A(s+3); bufC/bufN = LDS buf for s / s+1.
#define STEP(s, bC, bN, aW, aL, bufC, bufN) do {                             \
    if ((s) + 1 < NT) LOADB(bN, (s) + 1);                                    \
    if ((s) + 3 < NT) LOADA(aL, (s) + 3);                                    \
    COMPUTE(bufC, bC);                                                       \
    if ((s) + 1 < NT) { WRITEA(aW, bufN); LGKM_BARRIER(); }                  \
  } while (0)

  // prologue: B(0), A(0..2) in flight; stage A(0) into buf0.
  LOADB(bfrA, 0);
  LOADA(av0, 0);
  LOADA(av1, 1);
  LOADA(av2, 2);
  WRITEA(av0, 0);          // drains B(0)+A(0); A(1),A(2) stay in flight
  LGKM_BARRIER();

  STEP( 0, bfrA, bfrB, av1, av0, 0, 1);
  STEP( 1, bfrB, bfrA, av2, av1, 1, 0);
  STEP( 2, bfrA, bfrB, av0, av2, 0, 1);
  STEP( 3, bfrB, bfrA, av1, av0, 1, 0);
  STEP( 4, bfrA, bfrB, av2, av1, 0, 1);
  STEP( 5, bfrB, bfrA, av0, av2, 1, 0);
  STEP( 6, bfrA, bfrB, av1, av0, 0, 1);
  STEP( 7, bfrB, bfrA, av2, av1, 1, 0);
  STEP( 8, bfrA, bfrB, av0, av2, 0, 1);
  STEP( 9, bfrB, bfrA, av1, av0, 1, 0);
  STEP(10, bfrA, bfrB, av2, av1, 0, 1);
  STEP(11, bfrB, bfrA, av0, av2, 1, 0);
  STEP(12, bfrA, bfrB, av1, av0, 0, 1);
  STEP(13, bfrB, bfrA, av2, av1, 1, 0);
  STEP(14, bfrA, bfrB, av0, av2, 0, 1);
  STEP(15, bfrB, bfrA, av1, av0, 1, 0);

  __syncthreads();             // full drain before scratch aliases A buffer

#undef LOADA
#undef LOADB
#undef WRITEA
#undef COMPUTE
#undef STEP

  // ---- epilogue: tanh, row-softmax over 256 cols, store
  float* wred    = (float*)smem;           // [4 waves][64 rows]
  float* rowstat = (float*)(smem + 1024);  // [64 rows]

  float brow[4];
#pragma unroll
  for (int ni = 0; ni < 4; ++ni)
    brow[ni] = bias[(bidx << 8) + (wv << 6) + (ni << 4) + lr];

#pragma unroll
  for (int mi = 0; mi < 4; ++mi)
#pragma unroll
    for (int ni = 0; ni < 4; ++ni)
#pragma unroll
      for (int r = 0; r < 4; ++r)
        acc[mi][ni][r] = fast_tanh(acc[mi][ni][r] + brow[ni]);

  // per-row max: 4 local cols, then butterfly over the 16-lane col group
#pragma unroll
  for (int mi = 0; mi < 4; ++mi)
#pragma unroll
    for (int r = 0; r < 4; ++r) {
      float m = fmaxf(fmaxf(acc[mi][0][r], acc[mi][1][r]),
                      fmaxf(acc[mi][2][r], acc[mi][3][r]));
      m = fmaxf(m, __shfl_xor(m, 1));
      m = fmaxf(m, __shfl_xor(m, 2));
      m = fmaxf(m, __shfl_xor(m, 4));
      m = fmaxf(m, __shfl_xor(m, 8));
      if (lr == 0) wred[(wv << 6) + (mi << 4) + (lg << 2) + r] = m;
    }
  __syncthreads();
  if (tid < 64)
    rowstat[tid] = fmaxf(fmaxf(wred[tid], wred[64 + tid]),
                         fmaxf(wred[128 + tid], wred[192 + tid]));
  __syncthreads();

  // exp + per-row sum
#pragma unroll
  for (int mi = 0; mi < 4; ++mi)
#pragma unroll
    for (int r = 0; r < 4; ++r) {
      const int row = (mi << 4) + (lg << 2) + r;
      const float m = rowstat[row];
      float s = 0.f;
#pragma unroll
      for (int ni = 0; ni < 4; ++ni) {
        float e = __expf(acc[mi][ni][r] - m);
        acc[mi][ni][r] = e;
        s += e;
      }
      s += __shfl_xor(s, 1);
      s += __shfl_xor(s, 2);
      s += __shfl_xor(s, 4);
      s += __shfl_xor(s, 8);
      if (lr == 0) wred[(wv << 6) + row] = s;
    }
  __syncthreads();
  if (tid < 64)
    rowstat[tid] = 1.0f / (wred[tid] + wred[64 + tid] +
                           wred[128 + tid] + wred[192 + tid]);
  __syncthreads();

  // normalize + store (16 lanes = 64B dense segments)
#pragma unroll
  for (int mi = 0; mi < 4; ++mi)
#pragma unroll
    for (int r = 0; r < 4; ++r) {
      const int row = (mi << 4) + (lg << 2) + r;
      const float rinv = rowstat[row];
      float* orow = out + (size_t)(m0 + row) * KOUT + (wv << 6) + lr;
#pragma unroll
      for (int ni = 0; ni < 4; ++ni)
        orow[ni << 4] = acc[mi][ni][r] * rinv;
    }
}

extern "C" void kernel_launch(void* const* d_in, const int* in_sizes, int n_in,
                              void* d_out, int out_size, void* d_ws, size_t ws_size,
                              hipStream_t stream) {
  (void)in_sizes; (void)n_in; (void)out_size; (void)ws_size;
  const float* x   = (const float*)d_in[0];
  const float* y   = (const float*)d_in[1];
  const float* Wch = (const float*)d_in[2];
  const float* bch = (const float*)d_in[3];
  const float* Wy  = (const float*)d_in[4];
  float* out = (float*)d_out;
  unsigned short* wbf = (unsigned short*)d_ws;                 // 512 KB
  float* biasws = (float*)((char*)d_ws + 512 * 1024);          // 64 KB

  hipLaunchKernelGGL(prep_kernel, dim3(320), dim3(256), 0, stream,
                     Wch, y, Wy, bch, wbf, biasws);
  hipLaunchKernelGGL(fused_kernel, dim3(1024), dim3(256), 0, stream,
                     x, wbf, biasws, out);
}

// Round 9
// 111.424 us; speedup vs baseline: 1.8320x; 1.0629x over previous
//
#include <hip/hip_runtime.h>

// Problem: BS=64, N=1024, XC=1024, K=256, YS=768
//   y_k[b,k]   = sum_s y[b,s] * W_y[k,s]
//   z[b,n,k]   = tanh( sum_c x[b,n,c]*W_ch[k,c] + b_ch[k] + y_k[b,k] )
//   out[b*n,k] = softmax_k(z)
// bf16 MFMA GEMM (f32 acc) fused with tanh+softmax epilogue.
// R9: R8 + per-block K-phase rotation t0 = bid & 15. All x rows are 4KB
//     apart; without rotation every resident block reads the same 256B
//     column window mod 4096 simultaneously -> ~1/16 of HBM channels
//     active (power-of-2 stride pathology). Rotation uniformizes the
//     instantaneous address distribution across channels.

#define XC    1024
#define KOUT  256
#define NT    16        // K-steps: 1024 / 64
#define LDSZ  16384     // A double-buffer: 2 x 8KB (epilogue scratch aliases)

typedef float        f32x4_t  __attribute__((ext_vector_type(4)));
typedef unsigned int u32x4_t  __attribute__((ext_vector_type(4)));
typedef unsigned int u32x2_t  __attribute__((ext_vector_type(2)));
typedef __bf16       bf16x8_t __attribute__((ext_vector_type(8)));

__device__ __forceinline__ unsigned short f2bf(float f) {
  unsigned int u = __float_as_uint(f);
  u += 0x7fffu + ((u >> 16) & 1u);        // RNE
  return (unsigned short)(u >> 16);
}

__device__ __forceinline__ float fast_tanh(float v) {
  float e = __expf(2.0f * v);
  return 1.0f - 2.0f / (e + 1.0f);
}

// lgkm-only barrier: ds_writes visible, global loads STAY IN FLIGHT.
#define LGKM_BARRIER() do {                                  \
    asm volatile("s_waitcnt lgkmcnt(0)" ::: "memory");       \
    __builtin_amdgcn_s_barrier();                            \
    __builtin_amdgcn_sched_barrier(0);                       \
  } while (0)

// ---- prep kernel: blocks 0..255 convert W_ch -> fragment-ordered bf16;
//      blocks 256..319 compute bias[b][k] = y[b]·W_y[k] + b_ch[k] (f32).
// Fragment order: frag(t,wv,kk,ni) = ((t*4+wv)*2+kk)*4+ni, 64 lanes x 16B
// dense -> main kernel loads B with fully-coalesced 1KB global_load_dwordx4.
__global__ void prep_kernel(const float* __restrict__ Wch,
                            const float* __restrict__ y,
                            const float* __restrict__ Wy,
                            const float* __restrict__ bch,
                            unsigned short* __restrict__ wbf,
                            float* __restrict__ biasws) {
  if (blockIdx.x < 256) {
    const int k = blockIdx.x;            // 0..255
    const int u = threadIdx.x;           // 0..255 ; c0 = 4u
    f32x4_t v = ((const f32x4_t*)(Wch + k * XC))[u];
    const int c0   = u << 2;
    const int t    = c0 >> 6;            // K-step tile
    const int ch   = (c0 & 63) >> 3;     // 16B chunk within tile
    const int kk   = ch >> 2;
    const int lg   = ch & 3;
    const int half = (c0 >> 2) & 1;      // which 8B of the 16B chunk
    const int wv   = k >> 6;
    const int ni   = (k >> 4) & 3;
    const int lr   = k & 15;
    const int lane = (lg << 4) | lr;
    unsigned int lo = (unsigned int)f2bf(v.x) | ((unsigned int)f2bf(v.y) << 16);
    unsigned int hi = (unsigned int)f2bf(v.z) | ((unsigned int)f2bf(v.w) << 16);
    char* p = (char*)wbf +
              ((size_t)((((t << 2) + wv) * 2 + kk) * 4 + ni) << 10) +
              (lane << 4) + (half << 3);
    *(u32x2_t*)p = (u32x2_t){lo, hi};
  } else {
    __shared__ __align__(16) float ys[768];
    const int b = blockIdx.x - 256;      // 0..63
    const int k = threadIdx.x;           // 0..255
    for (int i = k; i < 768; i += 256) ys[i] = y[b * 768 + i];
    __syncthreads();
    const f32x4_t* w4 = (const f32x4_t*)(Wy + k * 768);
    const f32x4_t* y4 = (const f32x4_t*)ys;
    float s = 0.f;
#pragma unroll 8
    for (int i = 0; i < 192; ++i) {
      f32x4_t w = w4[i], a = y4[i];
      s = fmaf(w.x, a.x, s); s = fmaf(w.y, a.y, s);
      s = fmaf(w.z, a.z, s); s = fmaf(w.w, a.w, s);
    }
    biasws[b * 256 + k] = s + bch[k];
  }
}

// ---- main fused kernel: 64 rows/block x full 256 cols; BK=64.
// A: reg-staged f32->bf16, XOR-swizzled ds_write, dbuf LDS (16KB).
// B: fragment-ordered global loads straight to double-buffered registers.
__global__ __launch_bounds__(256, 2) void fused_kernel(
    const float* __restrict__ x, const unsigned short* __restrict__ wbf,
    const float* __restrict__ bias, float* __restrict__ out) {
  __shared__ __align__(16) unsigned char smem[LDSZ];
  const int tid = threadIdx.x;
  const int l   = tid & 63;
  const int wv  = tid >> 6;            // wave 0..3 -> output cols [64w,64w+64)
  const int lr  = l & 15;
  const int lg  = l >> 4;
  const int m0  = blockIdx.x << 6;     // first of 64 rows
  const int bidx = m0 >> 10;           // batch index
  const int rr  = tid >> 4;            // A-stage: row-within-16-group
  const int c4  = tid & 15;            // A-stage: float4 column chunk
  const int t0  = blockIdx.x & 15;     // per-block K-phase rotation

  f32x4_t acc[4][4];
#pragma unroll
  for (int i = 0; i < 4; ++i)
#pragma unroll
    for (int j = 0; j < 4; ++j) acc[i][j] = (f32x4_t){0.f, 0.f, 0.f, 0.f};

  const float* xb = x + (size_t)m0 * XC + (size_t)rr * XC + (c4 << 2);
  const char* wsrc = (const char*)wbf + (wv << 13) + (l << 4);
  f32x4_t av0[4], av1[4], av2[4];      // 3-deep A prefetch, NAMED slots
  bf16x8_t bfrA[8], bfrB[8];           // [kk*4+nj], double-buffered

#define LOADA(dst, tt) do {                                                  \
    _Pragma("unroll")                                                        \
    for (int j = 0; j < 4; ++j)                                              \
      dst[j] = *(const f32x4_t*)(xb + (size_t)(j << 4) * XC + ((tt) << 6));  \
  } while (0)

#define LOADB(dst, tt) do {                                                  \
    const char* g = wsrc + (size_t)(tt) * 32768;                             \
    _Pragma("unroll")                                                        \
    for (int f = 0; f < 8; ++f)                                              \
      dst[f] = __builtin_bit_cast(bf16x8_t, *(const u32x4_t*)(g + (f << 10)));\
  } while (0)

#define WRITEA(src, buf) do {                                                \
    _Pragma("unroll")                                                        \
    for (int j = 0; j < 4; ++j) {                                            \
      const int row = (j << 4) + rr;                                         \
      unsigned int lo = (unsigned int)f2bf(src[j].x) |                       \
                        ((unsigned int)f2bf(src[j].y) << 16);                \
      unsigned int hi = (unsigned int)f2bf(src[j].z) |                       \
                        ((unsigned int)f2bf(src[j].w) << 16);                \
      char* p = (char*)smem + ((buf) << 13) + row * 128 +                    \
                (((c4 >> 1) ^ (row & 7)) << 4) + ((c4 & 1) << 3);            \
      *(u32x2_t*)p = (u32x2_t){lo, hi};                                      \
    }                                                                        \
  } while (0)

#define COMPUTE(buf, bsrc) do {                                              \
    const u32x4_t* aB = (const u32x4_t*)(smem + ((buf) << 13));              \
    _Pragma("unroll")                                                        \
    for (int kk = 0; kk < 2; ++kk) {                                         \
      const int cs = ((kk << 2) | lg) ^ (lr & 7);                            \
      bf16x8_t afr[4];                                                       \
      _Pragma("unroll")                                                      \
      for (int mi = 0; mi < 4; ++mi)                                         \
        afr[mi] = __builtin_bit_cast(bf16x8_t, aB[(((mi << 4) + lr) << 3) + cs]);\
      _Pragma("unroll")                                                      \
      for (int mi = 0; mi < 4; ++mi)                                         \
        _Pragma("unroll")                                                    \
        for (int nj = 0; nj < 4; ++nj)                                       \
          acc[mi][nj] = __builtin_amdgcn_mfma_f32_16x16x32_bf16(             \
              afr[mi], bsrc[(kk << 2) | nj], acc[mi][nj], 0, 0, 0);          \
    }                                                                        \
  } while (0)

  // STEP(s): literal control flow; K-tile index rotated by t0 at runtime.
#define STEP(s, bC, bN, aW, aL, bufC, bufN) do {                             \
    if ((s) + 1 < NT) LOADB(bN, (((s) + 1 + t0) & 15));                      \
    if ((s) + 3 < NT) LOADA(aL, (((s) + 3 + t0) & 15));                      \
    COMPUTE(bufC, bC);                                                       \
    if ((s) + 1 < NT) { WRITEA(aW, bufN); LGKM_BARRIER(); }                  \
  } while (0)

  // prologue: B(t0), A(t0..t0+2) in flight; stage A(t0) into buf0.
  LOADB(bfrA, t0);
  LOADA(av0, t0);
  LOADA(av1, (t0 + 1) & 15);
  LOADA(av2, (t0 + 2) & 15);
  WRITEA(av0, 0);          // drains B+A(t0); later prefetches stay in flight
  LGKM_BARRIER();

  STEP( 0, bfrA, bfrB, av1, av0, 0, 1);
  STEP( 1, bfrB, bfrA, av2, av1, 1, 0);
  STEP( 2, bfrA, bfrB, av0, av2, 0, 1);
  STEP( 3, bfrB, bfrA, av1, av0, 1, 0);
  STEP( 4, bfrA, bfrB, av2, av1, 0, 1);
  STEP( 5, bfrB, bfrA, av0, av2, 1, 0);
  STEP( 6, bfrA, bfrB, av1, av0, 0, 1);
  STEP( 7, bfrB, bfrA, av2, av1, 1, 0);
  STEP( 8, bfrA, bfrB, av0, av2, 0, 1);
  STEP( 9, bfrB, bfrA, av1, av0, 1, 0);
  STEP(10, bfrA, bfrB, av2, av1, 0, 1);
  STEP(11, bfrB, bfrA, av0, av2, 1, 0);
  STEP(12, bfrA, bfrB, av1, av0, 0, 1);
  STEP(13, bfrB, bfrA, av2, av1, 1, 0);
  STEP(14, bfrA, bfrB, av0, av2, 0, 1);
  STEP(15, bfrB, bfrA, av1, av0, 1, 0);

  __syncthreads();             // full drain before scratch aliases A buffer

#undef LOADA
#undef LOADB
#undef WRITEA
#undef COMPUTE
#undef STEP

  // ---- epilogue: tanh, row-softmax over 256 cols, store
  float* wred    = (float*)smem;           // [4 waves][64 rows]
  float* rowstat = (float*)(smem + 1024);  // [64 rows]

  float brow[4];
#pragma unroll
  for (int ni = 0; ni < 4; ++ni)
    brow[ni] = bias[(bidx << 8) + (wv << 6) + (ni << 4) + lr];

#pragma unroll
  for (int mi = 0; mi < 4; ++mi)
#pragma unroll
    for (int ni = 0; ni < 4; ++ni)
#pragma unroll
      for (int r = 0; r < 4; ++r)
        acc[mi][ni][r] = fast_tanh(acc[mi][ni][r] + brow[ni]);

  // per-row max: 4 local cols, then butterfly over the 16-lane col group
#pragma unroll
  for (int mi = 0; mi < 4; ++mi)
#pragma unroll
    for (int r = 0; r < 4; ++r) {
      float m = fmaxf(fmaxf(acc[mi][0][r], acc[mi][1][r]),
                      fmaxf(acc[mi][2][r], acc[mi][3][r]));
      m = fmaxf(m, __shfl_xor(m, 1));
      m = fmaxf(m, __shfl_xor(m, 2));
      m = fmaxf(m, __shfl_xor(m, 4));
      m = fmaxf(m, __shfl_xor(m, 8));
      if (lr == 0) wred[(wv << 6) + (mi << 4) + (lg << 2) + r] = m;
    }
  __syncthreads();
  if (tid < 64)
    rowstat[tid] = fmaxf(fmaxf(wred[tid], wred[64 + tid]),
                         fmaxf(wred[128 + tid], wred[192 + tid]));
  __syncthreads();

  // exp + per-row sum
#pragma unroll
  for (int mi = 0; mi < 4; ++mi)
#pragma unroll
    for (int r = 0; r < 4; ++r) {
      const int row = (mi << 4) + (lg << 2) + r;
      const float m = rowstat[row];
      float s = 0.f;
#pragma unroll
      for (int ni = 0; ni < 4; ++ni) {
        float e = __expf(acc[mi][ni][r] - m);
        acc[mi][ni][r] = e;
        s += e;
      }
      s += __shfl_xor(s, 1);
      s += __shfl_xor(s, 2);
      s += __shfl_xor(s, 4);
      s += __shfl_xor(s, 8);
      if (lr == 0) wred[(wv << 6) + row] = s;
    }
  __syncthreads();
  if (tid < 64)
    rowstat[tid] = 1.0f / (wred[tid] + wred[64 + tid] +
                           wred[128 + tid] + wred[192 + tid]);
  __syncthreads();

  // normalize + store (16 lanes = 64B dense segments)
#pragma unroll
  for (int mi = 0; mi < 4; ++mi)
#pragma unroll
    for (int r = 0; r < 4; ++r) {
      const int row = (mi << 4) + (lg << 2) + r;
      const float rinv = rowstat[row];
      float* orow = out + (size_t)(m0 + row) * KOUT + (wv << 6) + lr;
#pragma unroll
      for (int ni = 0; ni < 4; ++ni)
        orow[ni << 4] = acc[mi][ni][r] * rinv;
    }
}

extern "C" void kernel_launch(void* const* d_in, const int* in_sizes, int n_in,
                              void* d_out, int out_size, void* d_ws, size_t ws_size,
                              hipStream_t stream) {
  (void)in_sizes; (void)n_in; (void)out_size; (void)ws_size;
  const float* x   = (const float*)d_in[0];
  const float* y   = (const float*)d_in[1];
  const float* Wch = (const float*)d_in[2];
  const float* bch = (const float*)d_in[3];
  const float* Wy  = (const float*)d_in[4];
  float* out = (float*)d_out;
  unsigned short* wbf = (unsigned short*)d_ws;                 // 512 KB
  float* biasws = (float*)((char*)d_ws + 512 * 1024);          // 64 KB

  hipLaunchKernelGGL(prep_kernel, dim3(320), dim3(256), 0, stream,
                     Wch, y, Wy, bch, wbf, biasws);
  hipLaunchKernelGGL(fused_kernel, dim3(1024), dim3(256), 0, stream,
                     x, wbf, biasws, out);
}